// Round 10
// baseline (22.157 us; speedup 1.0000x reference)
//
#include <hip/hip_runtime.h>

#define N_NODES 1024
#define B_SZ 16
#define F_SZ 50
#define CBLOCKS 2048
#define NITER (B_SZ * N_NODES / CBLOCKS)   // 8 rows per block

typedef float f32x4 __attribute__((ext_vector_type(4)));

// Kernel 1: port_has_track bits per (b, n), natural layout bits[b*N + n].
// port_feature_mask is a known constant 0/1 matrix: features 0-22 all-zero;
// port p sums exactly 7 features. Summing only nonzero features in
// ascending-f order is bitwise identical to the reference's masked
// accumulation (x + 0.0f == x exactly).
__global__ __launch_bounds__(64) void ports_kernel(
        const float* __restrict__ nf,
        unsigned char* __restrict__ bits) {
    int idx = blockIdx.x * 64 + threadIdx.x;  // b*N + n, 16384 total
    const float* r = nf + (size_t)idx * F_SZ;

    float f[27];
    #pragma unroll
    for (int q = 0; q < 27; ++q) f[q] = r[23 + q];  // features 23..49

    float a0 = (((((f[0]  + f[1])  + f[3])  + f[6])  + f[10]) + f[15]) + f[16];
    float a1 = (((((f[0]  + f[2])  + f[4])  + f[7])  + f[11]) + f[17]) + f[18];
    float a2 = (((((f[1]  + f[2])  + f[5])  + f[8])  + f[12]) + f[19]) + f[20];
    float a3 = (((((f[3]  + f[4])  + f[5])  + f[9])  + f[13]) + f[21]) + f[22];
    float a4 = (((((f[6]  + f[7])  + f[8])  + f[9])  + f[14]) + f[23]) + f[24];
    float a5 = (((((f[10] + f[11]) + f[12]) + f[13]) + f[14]) + f[25]) + f[26];

    unsigned m = 0;
    m |= (a0 > 0.0f) ? 1u  : 0u;
    m |= (a1 > 0.0f) ? 2u  : 0u;
    m |= (a2 > 0.0f) ? 4u  : 0u;
    m |= (a3 > 0.0f) ? 8u  : 0u;
    m |= (a4 > 0.0f) ? 16u : 0u;
    m |= (a5 > 0.0f) ? 32u : 0u;
    bits[idx] = (unsigned char)m;
}

// Kernel 2: out[b,i,j] = src_bit(b,i,d) & dst_bit(b,j,o) & (dir != 6)
// Persistent grid-strided: 2048 blocks (8/CU) x 8 iterations at stride 2048
// rows. Instantaneous chip-wide write front = one dense 8 MB sliding window.
// Software-pipelined: iteration k+1's loads are issued before iteration k's
// compute+store, so NT stores stream back-to-back and loads hide under them.
__global__ __launch_bounds__(256) void connect_kernel(
        const int* __restrict__ dir,
        const unsigned char* __restrict__ bits,
        float* __restrict__ out) {
    const int blk = blockIdx.x;         // 2048
    const int t = threadIdx.x;          // columns [4t, 4t+3]

    // prologue: loads for iteration 0
    int p = blk;                        // row index (b,i) = p>>10, p&1023
    int4 d = ((const int4*)(dir + (size_t)(p & (N_NODES - 1)) * N_NODES))[t];
    uchar4 t4 = ((const uchar4*)(bits + (p >> 10) * N_NODES))[t];
    unsigned s = bits[(p >> 10) * N_NODES + (p & (N_NODES - 1))];

    #pragma unroll
    for (int it = 0; it < NITER; ++it) {
        const int pc = p;
        int4 dc = d; uchar4 t4c = t4; unsigned sc = s;

        // issue next iteration's loads first (hide under compute+store)
        if (it + 1 < NITER) {
            p = blk + (it + 1) * CBLOCKS;
            d  = ((const int4*)(dir + (size_t)(p & (N_NODES - 1)) * N_NODES))[t];
            t4 = ((const uchar4*)(bits + (p >> 10) * N_NODES))[t];
            s  = bits[(p >> 10) * N_NODES + (p & (N_NODES - 1))];
        }

        int dvv[4] = {dc.x, dc.y, dc.z, dc.w};
        unsigned tv[4] = {t4c.x, t4c.y, t4c.z, t4c.w};
        f32x4 o;
        #pragma unroll
        for (int k = 0; k < 4; ++k) {
            int dval = dvv[k];
            unsigned am = (dval != 6) ? 1u : 0u;
            unsigned ds = (unsigned)min(dval, 5);
            unsigned os = (unsigned)min((dval + 3) % 6, 5);
            o[k] = ((sc >> ds) & (tv[k] >> os) & am & 1u) ? 1.0f : 0.0f;
        }
        __builtin_nontemporal_store(
            o, (f32x4*)(out + (size_t)pc * N_NODES) + t);
    }
}

extern "C" void kernel_launch(void* const* d_in, const int* in_sizes, int n_in,
                              void* d_out, int out_size, void* d_ws, size_t ws_size,
                              hipStream_t stream) {
    const float* nf  = (const float*)d_in[0];    // (16, 1024, 50) f32
    const int*   dir = (const int*)d_in[1];      // (1024, 1024) i32
    float* out = (float*)d_out;                  // (16, 1024, 1024) f32
    unsigned char* bits = (unsigned char*)d_ws;  // 16 KB scratch, [b][n]

    ports_kernel<<<(B_SZ * N_NODES) / 64, 64, 0, stream>>>(nf, bits);
    connect_kernel<<<CBLOCKS, 256, 0, stream>>>(dir, bits, out);
}